// Round 7
// baseline (2236.591 us; speedup 1.0000x reference)
//
#include <hip/hip_runtime.h>

#define S_LEN 2048
#define B_SZ  64
#define D_IN  128
#define H_SZ  128
#define G4    512   // 4*H

typedef __attribute__((ext_vector_type(4))) float     floatx4;
typedef __attribute__((ext_vector_type(2))) float     floatx2;
typedef __attribute__((ext_vector_type(8))) _Float16  half8;
typedef __attribute__((ext_vector_type(4))) _Float16  half4;
typedef __attribute__((ext_vector_type(2))) _Float16  half2_t;

// DPP quad_perm helper (VALU pipe). CTRL: xor1=0xB1, xor2=0x4E.
template<int CTRL>
__device__ __forceinline__ float qperm(float v) {
  return __int_as_float(
      __builtin_amdgcn_mov_dpp(__float_as_int(v), CTRL, 0xF, 0xF, true));
}

// half2 extraction from half8 — register aliasing, no union round-trip
template<int P>
__device__ __forceinline__ half2_t h2ext(half8 v) {
  return __builtin_shufflevector(v, v, 2 * P, 2 * P + 1);
}

// Workgroup barrier that drains ONLY lgkmcnt (LDS), leaving global loads/
// stores (vmcnt) in flight. __syncthreads() would drain vmcnt(0) each step.
__device__ __forceinline__ void lds_barrier() {
  asm volatile("s_waitcnt lgkmcnt(0)\n\ts_barrier" ::: "memory");
}

// ---------------------------------------------------------------------------
// Kernel 1: gx[b][n][t] = (sum_k X[t,b][k]*W_ih[n][k] + b[n]) * sc(type),
// stored f16 TRANSPOSED to [B][512][S] so lstm_rev reads 8 timesteps per
// load.  sc = -log2e for i,f,o; -2log2e for g.  Grid: (S/256, B).
// ---------------------------------------------------------------------------
__global__ __launch_bounds__(256) void gx_gemm(
    const float* __restrict__ X,       // [S*B][128] (row = t*64+b)
    const float* __restrict__ Wih,     // [512][128]
    const float* __restrict__ bias,    // [512]
    _Float16* __restrict__ gx)         // [64][512][2048] f16, pre-scaled
{
  __shared__ _Float16 Wl[128][136];
  const int tid  = threadIdx.x;
  const int lane = tid & 63;
  const int wv   = tid >> 6;
  const int b    = blockIdx.y;         // batch
  const int T0   = blockIdx.x * 256;   // time block
  const int m    = lane & 15;
  const int q    = lane >> 4;

  const float LOG2E = 1.4426950408889634f;

  // A-fragments: 4 row-groups of 64 t each; A-row = t, X row = t*64+b
  half8 afrag[4][4];
  #pragma unroll
  for (int rg = 0; rg < 4; ++rg) {
    const int t = T0 + rg * 64 + wv * 16 + m;
    const float* xrow = X + ((size_t)t * B_SZ + b) * D_IN;
    #pragma unroll
    for (int kf = 0; kf < 4; ++kf) {
      const int k0 = kf * 32 + q * 8;
      floatx4 v0 = *(const floatx4*)(xrow + k0);
      floatx4 v1 = *(const floatx4*)(xrow + k0 + 4);
      half8 a;
      a[0] = (_Float16)v0.x; a[1] = (_Float16)v0.y;
      a[2] = (_Float16)v0.z; a[3] = (_Float16)v0.w;
      a[4] = (_Float16)v1.x; a[5] = (_Float16)v1.y;
      a[6] = (_Float16)v1.z; a[7] = (_Float16)v1.w;
      afrag[rg][kf] = a;
    }
  }

  for (int nc = 0; nc < 4; ++nc) {      // gate-type chunk (128 gate rows)
    const float sc = (nc == 2) ? (-2.0f * LOG2E) : (-LOG2E);
    __syncthreads();
    for (int i = tid; i < 128 * 32; i += 256) {
      const int row = i >> 5;
      const int c4  = (i & 31) * 4;
      floatx4 v = *(const floatx4*)(Wih + ((size_t)nc * 128 + row) * D_IN + c4);
      Wl[row][c4 + 0] = (_Float16)v.x;
      Wl[row][c4 + 1] = (_Float16)v.y;
      Wl[row][c4 + 2] = (_Float16)v.z;
      Wl[row][c4 + 3] = (_Float16)v.w;
    }
    __syncthreads();

    #pragma unroll
    for (int nt = 0; nt < 8; ++nt) {
      const int n0  = nc * 128 + nt * 16;
      const int nlo = nt * 16 + m;
      const float bv = bias[n0 + m];
      half8 bfrag[4];
      #pragma unroll
      for (int kf = 0; kf < 4; ++kf)
        bfrag[kf] = *(const half8*)(&Wl[nlo][kf * 32 + q * 8]);
      #pragma unroll
      for (int rg = 0; rg < 4; ++rg) {
        floatx4 acc = {bv, bv, bv, bv};
        #pragma unroll
        for (int kf = 0; kf < 4; ++kf)
          acc = __builtin_amdgcn_mfma_f32_16x16x32_f16(afrag[rg][kf],
                                                       bfrag[kf], acc, 0, 0, 0);
        // C layout: col(n) = lane&15, row(t offset) = q*4 + reg
        const int tbase = T0 + rg * 64 + wv * 16 + q * 4;
        half4 hv;
        hv[0] = (_Float16)(acc[0] * sc);
        hv[1] = (_Float16)(acc[1] * sc);
        hv[2] = (_Float16)(acc[2] * sc);
        hv[3] = (_Float16)(acc[3] * sc);
        *(half4*)(gx + ((size_t)b * G4 + n0 + m) * S_LEN + tbase) = hv;
      }
    }
  }
}

// ---------------------------------------------------------------------------
// Kernel 2: reverse-time recurrence. ROUND 7: one WG per TWO batches
// (32 WGs x 512 thr). The substep is latency-bound: all 8 waves of a WG
// are barrier-locked to one serial chain (LDS h read -> dots -> butterfly
// -> activation -> write -> barrier), so 2 waves/SIMD can't hide it. Two
// INDEPENDENT gate chains per thread (batch b0, b0+1) fill the gaps, and
// one barrier covers two batch-steps. This is round-1's plan, now runnable:
// round 1 was invalidated by scratch-demoted weights (VGPR=60); with
// amdgpu_waves_per_eu(2,2) the budget is 256 and weights stay resident.
// Validity gate: VGPR_Count >= 140, no scratch.
// types: 0=i 1=f 2=g 3=o
// ---------------------------------------------------------------------------
__device__ __forceinline__ float fd(half2_t a, half2_t b, float c) {
  return __builtin_amdgcn_fdot2(a, b, c, false);
}

__device__ __forceinline__ half8 wcvt(const float* __restrict__ p, float sc) {
  floatx4 v0 = *(const floatx4*)p;
  floatx4 v1 = *(const floatx4*)(p + 4);
  half8 h;
  h[0] = (_Float16)(v0.x * sc); h[1] = (_Float16)(v0.y * sc);
  h[2] = (_Float16)(v0.z * sc); h[3] = (_Float16)(v0.w * sc);
  h[4] = (_Float16)(v1.x * sc); h[5] = (_Float16)(v1.y * sc);
  h[6] = (_Float16)(v1.z * sc); h[7] = (_Float16)(v1.w * sc);
  return h;
}

#define PIN_WEIGHTS()                                                         \
  asm volatile(""                                                             \
               : "+v"(w00), "+v"(w01), "+v"(w02), "+v"(w03),                  \
                 "+v"(w10), "+v"(w11), "+v"(w12), "+v"(w13),                  \
                 "+v"(w20), "+v"(w21), "+v"(w22), "+v"(w23),                  \
                 "+v"(w30), "+v"(w31), "+v"(w32), "+v"(w33),                  \
                 "+v"(wt), "+v"(bt))

// DOT8 over one h-fragment HV with the four gate-type weight frags WA..WD
#define DOT8(HV, WA, WB, WC, WD)                                              \
  {                                                                           \
    q0a = fd(h2ext<0>(HV), h2ext<0>(WA), q0a);                                \
    q1a = fd(h2ext<0>(HV), h2ext<0>(WB), q1a);                                \
    q2a = fd(h2ext<0>(HV), h2ext<0>(WC), q2a);                                \
    q3a = fd(h2ext<0>(HV), h2ext<0>(WD), q3a);                                \
    q0a = fd(h2ext<1>(HV), h2ext<1>(WA), q0a);                                \
    q1a = fd(h2ext<1>(HV), h2ext<1>(WB), q1a);                                \
    q2a = fd(h2ext<1>(HV), h2ext<1>(WC), q2a);                                \
    q3a = fd(h2ext<1>(HV), h2ext<1>(WD), q3a);                                \
    q0b = fd(h2ext<2>(HV), h2ext<2>(WA), q0b);                                \
    q1b = fd(h2ext<2>(HV), h2ext<2>(WB), q1b);                                \
    q2b = fd(h2ext<2>(HV), h2ext<2>(WC), q2b);                                \
    q3b = fd(h2ext<2>(HV), h2ext<2>(WD), q3b);                                \
    q0b = fd(h2ext<3>(HV), h2ext<3>(WA), q0b);                                \
    q1b = fd(h2ext<3>(HV), h2ext<3>(WB), q1b);                                \
    q2b = fd(h2ext<3>(HV), h2ext<3>(WD), q2b);                                \
    q3b = fd(h2ext<3>(HV), h2ext<3>(WD), q3b);                                \
  }

// NOTE: the two lines above had a typo risk; define explicitly correct:
#undef DOT8
#define DOT8(HV, WA, WB, WC, WD)                                              \
  {                                                                           \
    q0a = fd(h2ext<0>(HV), h2ext<0>(WA), q0a);                                \
    q1a = fd(h2ext<0>(HV), h2ext<0>(WB), q1a);                                \
    q2a = fd(h2ext<0>(HV), h2ext<0>(WC), q2a);                                \
    q3a = fd(h2ext<0>(HV), h2ext<0>(WD), q3a);                                \
    q0a = fd(h2ext<1>(HV), h2ext<1>(WA), q0a);                                \
    q1a = fd(h2ext<1>(HV), h2ext<1>(WB), q1a);                                \
    q2a = fd(h2ext<1>(HV), h2ext<1>(WC), q2a);                                \
    q3a = fd(h2ext<1>(HV), h2ext<1>(WD), q3a);                                \
    q0b = fd(h2ext<2>(HV), h2ext<2>(WA), q0b);                                \
    q1b = fd(h2ext<2>(HV), h2ext<2>(WB), q1b);                                \
    q2b = fd(h2ext<2>(HV), h2ext<2>(WC), q2b);                                \
    q3b = fd(h2ext<2>(HV), h2ext<2>(WD), q3b);                                \
    q0b = fd(h2ext<3>(HV), h2ext<3>(WA), q0b);                                \
    q1b = fd(h2ext<3>(HV), h2ext<3>(WB), q1b);                                \
    q2b = fd(h2ext<3>(HV), h2ext<3>(WC), q2b);                                \
    q3b = fd(h2ext<3>(HV), h2ext<3>(WD), q3b);                                \
  }

// Full gate pipeline for one batch, one step.
#define GATE(HR, GXV, TMV, CVAR, HVAR)                                        \
  {                                                                           \
    half8 hv0 = *(const half8*)((HR) + 0 * 32 + tt * 8);                      \
    half8 hv1 = *(const half8*)((HR) + 1 * 32 + tt * 8);                      \
    half8 hv2 = *(const half8*)((HR) + 2 * 32 + tt * 8);                      \
    half8 hv3 = *(const half8*)((HR) + 3 * 32 + tt * 8);                      \
    float q0a = 0.f, q0b = 0.f, q1a = 0.f, q1b = 0.f;                         \
    float q2a = 0.f, q2b = 0.f, q3a = 0.f, q3b = 0.f;                         \
    DOT8(hv0, w00, w10, w20, w30);                                            \
    DOT8(hv1, w01, w11, w21, w31);                                            \
    DOT8(hv2, w02, w12, w22, w32);                                            \
    DOT8(hv3, w03, w13, w23, w33);                                            \
    float a0 = q0a + q0b, a1 = q1a + q1b, a2 = q2a + q2b, a3 = q3a + q3b;     \
    a0 += qperm<0xB1>(a0); a1 += qperm<0xB1>(a1);                             \
    a2 += qperm<0xB1>(a2); a3 += qperm<0xB1>(a3);                             \
    a0 += qperm<0x4E>(a0); a1 += qperm<0x4E>(a1);                             \
    a2 += qperm<0x4E>(a2); a3 += qperm<0x4E>(a3);                             \
    float pre = (tt & 1) ? ((tt & 2) ? a3 : a1) : ((tt & 2) ? a2 : a0);       \
    pre += (GXV);  /* already scaled by -log2e (or -2log2e for g) */          \
    const float e  = __builtin_amdgcn_exp2f(pre);                             \
    const float v  = fmaf(am, __builtin_amdgcn_rcpf(1.0f + e), aa);           \
    float z = fmaf((TMV), wt, bt);           /* = -log2e*(t*w_t+b_t) */       \
    z = fminf(z, 0.0f);                      /* -log2e*relu(.) */             \
    const float d  = __builtin_amdgcn_exp2f(z);                               \
    const float p2 = qperm<0x4E>(v);                                          \
    const float fv = (tt == 1) ? v : p2;                                      \
    const float r  = odd ? fv * (d * (CVAR)) : v * p2;                        \
    const float cn = r + qperm<0xB1>(r);                                      \
    (CVAR) = cn;                                                              \
    const float e2 = __builtin_amdgcn_exp2f(-2.0f * LOG2E * cn);              \
    const float th = fmaf(2.0f, __builtin_amdgcn_rcpf(1.0f + e2), -1.0f);     \
    (HVAR) = v * th;                                                          \
  }

// One substep for BOTH batches. K: index into cur8* (t = blk*8+K).
// TM0/TM1: staged times for b0/b0+1. RP/WP: ping-pong indices.
#define SUB2(K, TM0, TM1, RP, WP)                                             \
  {                                                                           \
    const float g0 = (float)cura[K];                                          \
    const float g1 = (float)curb[K];                                          \
    float h0, h1;                                                             \
    GATE(&hbuf[0][RP][0], g0, (TM0), c0, h0);                                 \
    GATE(&hbuf[1][RP][0], g1, (TM1), c1, h1);                                 \
    if (tt == 3) {                                                            \
      hbuf[0][WP][col] = (_Float16)h0;                                        \
      hbuf[1][WP][col] = (_Float16)h1;                                        \
      const int tcur = blk * 8 + K;                                           \
      float* o = out + ((size_t)tcur << 13) + b0H + col;                      \
      o[0]    = h0;                                                           \
      o[H_SZ] = h1;                                                           \
      if (tcur == 0) {                                                        \
        float* hf = out + (size_t)S_LEN * B_SZ * H_SZ;                        \
        hf[b0H + col]        = h0;                                            \
        hf[b0H + H_SZ + col] = h1;                                            \
        float* cf = hf + (size_t)B_SZ * H_SZ;                                 \
        cf[b0H + col]        = c0;                                            \
        cf[b0H + H_SZ + col] = c1;                                            \
      }                                                                       \
    }                                                                         \
    lds_barrier();                                                            \
  }

__global__ __launch_bounds__(512)
__attribute__((amdgpu_waves_per_eu(2, 2)))
void lstm_rev(
    const _Float16* __restrict__ gx,        // [64][512][2048] f16, pre-scaled
    const float* __restrict__ timep,        // [S*B]
    const float* __restrict__ Whh,          // [512][128]
    const float* __restrict__ w_tp,         // [128]
    const float* __restrict__ b_tp,         // [128]
    float* __restrict__ out)                // S*B*H outputs, then h, then c
{
  __shared__ __align__(16) _Float16 hbuf[2][2][H_SZ];  // [batch][pp][col]
  __shared__ __align__(16) floatx2  tml[S_LEN];        // {t[b0], t[b0+1]} 16KB
  const int tid = threadIdx.x;
  const int b0  = blockIdx.x * 2;            // this WG's two batches
  const int tt  = tid & 3;
  const int col = tid >> 2;
  const int j   = tt * 128 + col;

  const float LOG2E = 1.4426950408889634f;

  // Stage both batches' time columns into LDS (one-time, 8 loads/thread).
  #pragma unroll
  for (int k = 0; k < 4; ++k) {
    const int idx = tid + k * 512;
    floatx2 tv;
    tv.x = timep[(idx << 6) + b0];
    tv.y = timep[(idx << 6) + b0 + 1];
    tml[idx] = tv;
  }

  // Pre-scaled f16 weights in 16 NAMED registers (shared by both batches):
  // wTI = sc(T) * W_hh[T*128+col][I*32+tt*8 .. +7].
  half8 w00, w01, w02, w03, w10, w11, w12, w13;
  half8 w20, w21, w22, w23, w30, w31, w32, w33;
  {
    const float s1 = -LOG2E, s2 = -2.0f * LOG2E;
    const float* r0 = Whh + (size_t)(0 * 128 + col) * H_SZ + tt * 8;
    const float* r1 = Whh + (size_t)(1 * 128 + col) * H_SZ + tt * 8;
    const float* r2 = Whh + (size_t)(2 * 128 + col) * H_SZ + tt * 8;
    const float* r3 = Whh + (size_t)(3 * 128 + col) * H_SZ + tt * 8;
    w00 = wcvt(r0 +  0, s1); w01 = wcvt(r0 + 32, s1);
    w02 = wcvt(r0 + 64, s1); w03 = wcvt(r0 + 96, s1);
    w10 = wcvt(r1 +  0, s1); w11 = wcvt(r1 + 32, s1);
    w12 = wcvt(r1 + 64, s1); w13 = wcvt(r1 + 96, s1);
    w20 = wcvt(r2 +  0, s2); w21 = wcvt(r2 + 32, s2);
    w22 = wcvt(r2 + 64, s2); w23 = wcvt(r2 + 96, s2);
    w30 = wcvt(r3 +  0, s1); w31 = wcvt(r3 + 32, s1);
    w32 = wcvt(r3 + 64, s1); w33 = wcvt(r3 + 96, s1);
  }

  float wt = -LOG2E * w_tp[col];
  float bt = -LOG2E * b_tp[col];
  const float am  = (tt == 2) ? 2.0f : 1.0f;
  const float aa  = (tt == 2) ? -1.0f : 0.0f;
  const bool  odd = (tt & 1) != 0;

  ((_Float16*)hbuf)[tid] = (_Float16)0.0f;   // 2*2*128 = 512 = blockDim
  __syncthreads();

  // Per-thread gate-x rows: 2048 consecutive f16 each.
  const _Float16* gxra = gx + ((size_t)b0 * G4 + j) * S_LEN;
  const _Float16* gxrb = gxra + (size_t)G4 * S_LEN;
  const size_t b0H = (size_t)b0 * H_SZ;

  // Double-buffered half8 blocks, 2 blocks (~16 substeps) ahead of use.
  half8 cura = *(const half8*)(gxra + 255 * 8);
  half8 curb = *(const half8*)(gxrb + 255 * 8);
  half8 nxta = *(const half8*)(gxra + 254 * 8);
  half8 nxtb = *(const half8*)(gxrb + 254 * 8);

  float c0 = 0.0f, c1 = 0.0f;

  for (int blk = 255; blk >= 0; --blk) {
    PIN_WEIGHTS();
    const int pfb = (blk >= 2) ? blk - 2 : 0;
    half8 futa = *(const half8*)(gxra + pfb * 8);
    half8 futb = *(const half8*)(gxrb + pfb * 8);
    // Staged times for this block: tmQk covers t = blk*8 + 2k, 2k+1
    const floatx4 tmQ0 = *(const floatx4*)(&tml[blk * 8 + 0]);
    const floatx4 tmQ1 = *(const floatx4*)(&tml[blk * 8 + 2]);
    const floatx4 tmQ2 = *(const floatx4*)(&tml[blk * 8 + 4]);
    const floatx4 tmQ3 = *(const floatx4*)(&tml[blk * 8 + 6]);

    // 8 substeps: t = blk*8+7 down to blk*8 (ping-pong parity returns to 0)
    SUB2(7, tmQ3.z, tmQ3.w, 0, 1)
    SUB2(6, tmQ3.x, tmQ3.y, 1, 0)
    SUB2(5, tmQ2.z, tmQ2.w, 0, 1)
    SUB2(4, tmQ2.x, tmQ2.y, 1, 0)
    SUB2(3, tmQ1.z, tmQ1.w, 0, 1)
    SUB2(2, tmQ1.x, tmQ1.y, 1, 0)
    SUB2(1, tmQ0.z, tmQ0.w, 0, 1)
    SUB2(0, tmQ0.x, tmQ0.y, 1, 0)

    cura = nxta; nxta = futa;
    curb = nxtb; nxtb = futb;
  }
}

// ---------------------------------------------------------------------------
extern "C" void kernel_launch(void* const* d_in, const int* in_sizes, int n_in,
                              void* d_out, int out_size, void* d_ws, size_t ws_size,
                              hipStream_t stream) {
  const float* input = (const float*)d_in[0];   // (S,B,D)
  const float* timep = (const float*)d_in[1];   // (S,B,1)
  const float* W_ih  = (const float*)d_in[2];   // (4H,D)
  const float* W_hh  = (const float*)d_in[3];   // (4H,H)
  const float* bias  = (const float*)d_in[4];   // (4H,)
  const float* w_t   = (const float*)d_in[5];   // (H,)
  const float* b_t   = (const float*)d_in[6];   // (H,)
  float* out = (float*)d_out;

  _Float16* gx = (_Float16*)d_ws;   // 64*512*2048*2 = 128 MiB, [b][n][t]

  gx_gemm<<<dim3(S_LEN / 256, B_SZ), dim3(256), 0, stream>>>(
      input, W_ih, bias, gx);

  lstm_rev<<<dim3(B_SZ / 2), dim3(512), 0, stream>>>(
      gx, timep, W_hh, w_t, b_t, out);
}

// Round 8
// 1343.794 us; speedup vs baseline: 1.6644x; 1.6644x over previous
//
#include <hip/hip_runtime.h>

#define S_LEN 2048
#define B_SZ  64
#define D_IN  128
#define H_SZ  128
#define G4    512   // 4*H

typedef __attribute__((ext_vector_type(4))) float     floatx4;
typedef __attribute__((ext_vector_type(2))) float     floatx2;
typedef __attribute__((ext_vector_type(8))) _Float16  half8;
typedef __attribute__((ext_vector_type(4))) _Float16  half4;
typedef __attribute__((ext_vector_type(2))) _Float16  half2_t;

// DPP quad_perm helper (VALU pipe). CTRL: xor1=0xB1, xor2=0x4E.
template<int CTRL>
__device__ __forceinline__ float qperm(float v) {
  return __int_as_float(
      __builtin_amdgcn_mov_dpp(__float_as_int(v), CTRL, 0xF, 0xF, true));
}

template<int P>
__device__ __forceinline__ half2_t h2ext(half8 v) {
  return __builtin_shufflevector(v, v, 2 * P, 2 * P + 1);
}

// Barrier draining ONLY lgkmcnt (LDS); global loads/stores stay in flight.
__device__ __forceinline__ void lds_barrier() {
  asm volatile("s_waitcnt lgkmcnt(0)\n\ts_barrier" ::: "memory");
}

// ---------------------------------------------------------------------------
// Kernel 1: gx[b][n][t] = (sum_k X[t,b][k]*W_ih[n][k] + b[n]) * sc(type),
// f16, TRANSPOSED to [B][512][S] so lstm_rev reads 8 timesteps per load.
// sc = -log2e for i,f,o; -2log2e for g.  Grid: (S/256, B).
// ---------------------------------------------------------------------------
__global__ __launch_bounds__(256) void gx_gemm(
    const float* __restrict__ X,       // [S*B][128] (row = t*64+b)
    const float* __restrict__ Wih,     // [512][128]
    const float* __restrict__ bias,    // [512]
    _Float16* __restrict__ gx)         // [64][512][2048] f16, pre-scaled
{
  __shared__ _Float16 Wl[128][136];
  const int tid  = threadIdx.x;
  const int lane = tid & 63;
  const int wv   = tid >> 6;
  const int b    = blockIdx.y;
  const int T0   = blockIdx.x * 256;
  const int m    = lane & 15;
  const int q    = lane >> 4;

  const float LOG2E = 1.4426950408889634f;

  half8 afrag[4][4];
  #pragma unroll
  for (int rg = 0; rg < 4; ++rg) {
    const int t = T0 + rg * 64 + wv * 16 + m;
    const float* xrow = X + ((size_t)t * B_SZ + b) * D_IN;
    #pragma unroll
    for (int kf = 0; kf < 4; ++kf) {
      const int k0 = kf * 32 + q * 8;
      floatx4 v0 = *(const floatx4*)(xrow + k0);
      floatx4 v1 = *(const floatx4*)(xrow + k0 + 4);
      half8 a;
      a[0] = (_Float16)v0.x; a[1] = (_Float16)v0.y;
      a[2] = (_Float16)v0.z; a[3] = (_Float16)v0.w;
      a[4] = (_Float16)v1.x; a[5] = (_Float16)v1.y;
      a[6] = (_Float16)v1.z; a[7] = (_Float16)v1.w;
      afrag[rg][kf] = a;
    }
  }

  for (int nc = 0; nc < 4; ++nc) {
    const float sc = (nc == 2) ? (-2.0f * LOG2E) : (-LOG2E);
    __syncthreads();
    for (int i = tid; i < 128 * 32; i += 256) {
      const int row = i >> 5;
      const int c4  = (i & 31) * 4;
      floatx4 v = *(const floatx4*)(Wih + ((size_t)nc * 128 + row) * D_IN + c4);
      Wl[row][c4 + 0] = (_Float16)v.x;
      Wl[row][c4 + 1] = (_Float16)v.y;
      Wl[row][c4 + 2] = (_Float16)v.z;
      Wl[row][c4 + 3] = (_Float16)v.w;
    }
    __syncthreads();

    #pragma unroll
    for (int nt = 0; nt < 8; ++nt) {
      const int n0  = nc * 128 + nt * 16;
      const int nlo = nt * 16 + m;
      const float bv = bias[n0 + m];
      half8 bfrag[4];
      #pragma unroll
      for (int kf = 0; kf < 4; ++kf)
        bfrag[kf] = *(const half8*)(&Wl[nlo][kf * 32 + q * 8]);
      #pragma unroll
      for (int rg = 0; rg < 4; ++rg) {
        floatx4 acc = {bv, bv, bv, bv};
        #pragma unroll
        for (int kf = 0; kf < 4; ++kf)
          acc = __builtin_amdgcn_mfma_f32_16x16x32_f16(afrag[rg][kf],
                                                       bfrag[kf], acc, 0, 0, 0);
        const int tbase = T0 + rg * 64 + wv * 16 + q * 4;
        half4 hv;
        hv[0] = (_Float16)(acc[0] * sc);
        hv[1] = (_Float16)(acc[1] * sc);
        hv[2] = (_Float16)(acc[2] * sc);
        hv[3] = (_Float16)(acc[3] * sc);
        *(half4*)(gx + ((size_t)b * G4 + n0 + m) * S_LEN + tbase) = hv;
      }
    }
  }
}

// ---------------------------------------------------------------------------
// Kernel 2: reverse-time recurrence. ROUND 8: one WG per batch, 256 threads
// (4 waves, 1 wave/SIMD), each thread computes TWO gates (hidden cols col
// and col+64, same k-slice tt). Same issue per SIMD as the 512-thr version
// but: two independent chains inside each thread (compiler must interleave
// — shared hv loads merge the region, unlike R7's serializable dual-GATE),
// halved LDS read requests, 4-wave barrier, no inter-wave SIMD contention.
// amdgpu_waves_per_eu(1,1): 512-VGPR budget so the ~210-reg working set
// (128 weight VGPRs) stays resident. Validity gate: VGPR_Count >= 180.
// types: 0=i 1=f 2=g 3=o
// ---------------------------------------------------------------------------
__device__ __forceinline__ float fd(half2_t a, half2_t b, float c) {
  return __builtin_amdgcn_fdot2(a, b, c, false);
}

__device__ __forceinline__ half8 wcvt(const float* __restrict__ p, float sc) {
  floatx4 v0 = *(const floatx4*)p;
  floatx4 v1 = *(const floatx4*)(p + 4);
  half8 h;
  h[0] = (_Float16)(v0.x * sc); h[1] = (_Float16)(v0.y * sc);
  h[2] = (_Float16)(v0.z * sc); h[3] = (_Float16)(v0.w * sc);
  h[4] = (_Float16)(v1.x * sc); h[5] = (_Float16)(v1.y * sc);
  h[6] = (_Float16)(v1.z * sc); h[7] = (_Float16)(v1.w * sc);
  return h;
}

#define PIN_A()                                                               \
  asm volatile(""                                                             \
               : "+v"(wa00), "+v"(wa01), "+v"(wa02), "+v"(wa03),              \
                 "+v"(wa10), "+v"(wa11), "+v"(wa12), "+v"(wa13),              \
                 "+v"(wa20), "+v"(wa21), "+v"(wa22), "+v"(wa23),              \
                 "+v"(wa30), "+v"(wa31), "+v"(wa32), "+v"(wa33),              \
                 "+v"(wtA), "+v"(btA))
#define PIN_B()                                                               \
  asm volatile(""                                                             \
               : "+v"(wb00), "+v"(wb01), "+v"(wb02), "+v"(wb03),              \
                 "+v"(wb10), "+v"(wb11), "+v"(wb12), "+v"(wb13),              \
                 "+v"(wb20), "+v"(wb21), "+v"(wb22), "+v"(wb23),              \
                 "+v"(wb30), "+v"(wb31), "+v"(wb32), "+v"(wb33),              \
                 "+v"(wtB), "+v"(btB))

// Accumulate one h-fragment HV against gate-type weight frags W0..W3 into
// accumulators Q##0a..Q##3b (token-pasted prefix).
#define DOT8P(Q, HV, W0, W1, W2, W3)                                          \
  {                                                                           \
    Q##0a = fd(h2ext<0>(HV), h2ext<0>(W0), Q##0a);                            \
    Q##1a = fd(h2ext<0>(HV), h2ext<0>(W1), Q##1a);                            \
    Q##2a = fd(h2ext<0>(HV), h2ext<0>(W2), Q##2a);                            \
    Q##3a = fd(h2ext<0>(HV), h2ext<0>(W3), Q##3a);                            \
    Q##0a = fd(h2ext<1>(HV), h2ext<1>(W0), Q##0a);                            \
    Q##1a = fd(h2ext<1>(HV), h2ext<1>(W1), Q##1a);                            \
    Q##2a = fd(h2ext<1>(HV), h2ext<1>(W2), Q##2a);                            \
    Q##3a = fd(h2ext<1>(HV), h2ext<1>(W3), Q##3a);                            \
    Q##0b = fd(h2ext<2>(HV), h2ext<2>(W0), Q##0b);                            \
    Q##1b = fd(h2ext<2>(HV), h2ext<2>(W1), Q##1b);                            \
    Q##2b = fd(h2ext<2>(HV), h2ext<2>(W2), Q##2b);                            \
    Q##3b = fd(h2ext<2>(HV), h2ext<2>(W3), Q##3b);                            \
    Q##0b = fd(h2ext<3>(HV), h2ext<3>(W0), Q##0b);                            \
    Q##1b = fd(h2ext<3>(HV), h2ext<3>(W1), Q##1b);                            \
    Q##2b = fd(h2ext<3>(HV), h2ext<3>(W2), Q##2b);                            \
    Q##3b = fd(h2ext<3>(HV), h2ext<3>(W3), Q##3b);                            \
  }

// Activation chain: PRE (scaled pre-activation incl. gx), TMV time value,
// WT/BT per-col decay params, CV running c (updated), HOUT result h.
#define ACT(PRE, TMV, WT, BT, CV, HOUT)                                       \
  {                                                                           \
    const float e  = __builtin_amdgcn_exp2f(PRE);                             \
    const float v  = fmaf(am, __builtin_amdgcn_rcpf(1.0f + e), aa);           \
    float z = fmaf((TMV), (WT), (BT));                                        \
    z = fminf(z, 0.0f);                                                       \
    const float d  = __builtin_amdgcn_exp2f(z);                               \
    const float p2 = qperm<0x4E>(v);                                          \
    const float fv = (tt == 1) ? v : p2;                                      \
    const float r  = odd ? fv * (d * (CV)) : v * p2;                          \
    const float cn = r + qperm<0xB1>(r);                                      \
    (CV) = cn;                                                                \
    const float e2 = __builtin_amdgcn_exp2f(-2.0f * LOG2E * cn);              \
    const float th = fmaf(2.0f, __builtin_amdgcn_rcpf(1.0f + e2), -1.0f);     \
    (HOUT) = v * th;                                                          \
  }

// One substep: both gates of this thread. K: lane into cur8 (t = blk*8+K).
#define SUB2(K, TMV, RP, WP)                                                  \
  {                                                                           \
    const float g0 = (float)cur0[K];                                          \
    const float g1 = (float)cur1[K];                                          \
    half8 hv0 = *(const half8*)(&hbuf[RP][0] + 0 * 32 + tt * 8);              \
    half8 hv1 = *(const half8*)(&hbuf[RP][0] + 1 * 32 + tt * 8);              \
    half8 hv2 = *(const half8*)(&hbuf[RP][0] + 2 * 32 + tt * 8);              \
    half8 hv3 = *(const half8*)(&hbuf[RP][0] + 3 * 32 + tt * 8);              \
    float qa0a = 0.f, qa0b = 0.f, qa1a = 0.f, qa1b = 0.f;                     \
    float qa2a = 0.f, qa2b = 0.f, qa3a = 0.f, qa3b = 0.f;                     \
    float qb0a = 0.f, qb0b = 0.f, qb1a = 0.f, qb1b = 0.f;                     \
    float qb2a = 0.f, qb2b = 0.f, qb3a = 0.f, qb3b = 0.f;                     \
    DOT8P(qa, hv0, wa00, wa10, wa20, wa30);                                   \
    DOT8P(qb, hv0, wb00, wb10, wb20, wb30);                                   \
    DOT8P(qa, hv1, wa01, wa11, wa21, wa31);                                   \
    DOT8P(qb, hv1, wb01, wb11, wb21, wb31);                                   \
    DOT8P(qa, hv2, wa02, wa12, wa22, wa32);                                   \
    DOT8P(qb, hv2, wb02, wb12, wb22, wb32);                                   \
    DOT8P(qa, hv3, wa03, wa13, wa23, wa33);                                   \
    DOT8P(qb, hv3, wb03, wb13, wb23, wb33);                                   \
    float aA0 = qa0a + qa0b, aA1 = qa1a + qa1b;                               \
    float aA2 = qa2a + qa2b, aA3 = qa3a + qa3b;                               \
    float aB0 = qb0a + qb0b, aB1 = qb1a + qb1b;                               \
    float aB2 = qb2a + qb2b, aB3 = qb3a + qb3b;                               \
    aA0 += qperm<0xB1>(aA0); aA1 += qperm<0xB1>(aA1);                         \
    aA2 += qperm<0xB1>(aA2); aA3 += qperm<0xB1>(aA3);                         \
    aB0 += qperm<0xB1>(aB0); aB1 += qperm<0xB1>(aB1);                         \
    aB2 += qperm<0xB1>(aB2); aB3 += qperm<0xB1>(aB3);                         \
    aA0 += qperm<0x4E>(aA0); aA1 += qperm<0x4E>(aA1);                         \
    aA2 += qperm<0x4E>(aA2); aA3 += qperm<0x4E>(aA3);                         \
    aB0 += qperm<0x4E>(aB0); aB1 += qperm<0x4E>(aB1);                         \
    aB2 += qperm<0x4E>(aB2); aB3 += qperm<0x4E>(aB3);                         \
    float preA = (tt & 1) ? ((tt & 2) ? aA3 : aA1) : ((tt & 2) ? aA2 : aA0);  \
    float preB = (tt & 1) ? ((tt & 2) ? aB3 : aB1) : ((tt & 2) ? aB2 : aB0);  \
    preA += g0;                                                               \
    preB += g1;                                                               \
    float hA, hB;                                                             \
    ACT(preA, (TMV), wtA, btA, cA, hA);                                       \
    ACT(preB, (TMV), wtB, btB, cB, hB);                                       \
    if (tt == 3) {                                                            \
      hbuf[WP][col]      = (_Float16)hA;                                      \
      hbuf[WP][col + 64] = (_Float16)hB;                                      \
      const int tcur = blk * 8 + K;                                           \
      float* o = out + ((size_t)tcur << 13) + bH + col;                       \
      o[0]  = hA;                                                             \
      o[64] = hB;                                                             \
      if (tcur == 0) {                                                        \
        float* hf = out + (size_t)S_LEN * B_SZ * H_SZ;                        \
        hf[bH + col]      = hA;                                               \
        hf[bH + col + 64] = hB;                                               \
        float* cf = hf + (size_t)B_SZ * H_SZ;                                 \
        cf[bH + col]      = cA;                                               \
        cf[bH + col + 64] = cB;                                               \
      }                                                                       \
    }                                                                         \
    lds_barrier();                                                            \
  }

__global__ __launch_bounds__(256)
__attribute__((amdgpu_waves_per_eu(1, 1)))
void lstm_rev(
    const _Float16* __restrict__ gx,        // [64][512][2048] f16, pre-scaled
    const float* __restrict__ timep,        // [S*B]
    const float* __restrict__ Whh,          // [512][128]
    const float* __restrict__ w_tp,         // [128]
    const float* __restrict__ b_tp,         // [128]
    float* __restrict__ out)                // S*B*H outputs, then h, then c
{
  __shared__ __align__(16) _Float16 hbuf[2][H_SZ];   // ping-pong prev-h
  __shared__ __align__(16) float    tml[S_LEN];      // staged timep[.,b] 8KB
  const int tid = threadIdx.x;               // 0..255
  const int b   = blockIdx.x;                // one batch per WG
  const int tt  = tid & 3;
  const int col = tid >> 2;                  // 0..63
  const int j0  = tt * 128 + col;
  const int j1  = j0 + 64;

  const float LOG2E = 1.4426950408889634f;

  // Stage this batch's time column into LDS (8 loads/thread).
  #pragma unroll
  for (int k = 0; k < 8; ++k) {
    const int idx = tid + k * 256;
    tml[idx] = timep[(idx << 6) + b];
  }

  // Pre-scaled f16 weights, 32 NAMED registers: waTI for hidden col,
  // wbTI for hidden col+64.  wTI = sc(T) * W_hh[T*128+c][I*32+tt*8 .. +7].
  half8 wa00, wa01, wa02, wa03, wa10, wa11, wa12, wa13;
  half8 wa20, wa21, wa22, wa23, wa30, wa31, wa32, wa33;
  half8 wb00, wb01, wb02, wb03, wb10, wb11, wb12, wb13;
  half8 wb20, wb21, wb22, wb23, wb30, wb31, wb32, wb33;
  {
    const float s1 = -LOG2E, s2 = -2.0f * LOG2E;
    const float* a0 = Whh + (size_t)(0 * 128 + col) * H_SZ + tt * 8;
    const float* a1 = Whh + (size_t)(1 * 128 + col) * H_SZ + tt * 8;
    const float* a2 = Whh + (size_t)(2 * 128 + col) * H_SZ + tt * 8;
    const float* a3 = Whh + (size_t)(3 * 128 + col) * H_SZ + tt * 8;
    wa00 = wcvt(a0 +  0, s1); wa01 = wcvt(a0 + 32, s1);
    wa02 = wcvt(a0 + 64, s1); wa03 = wcvt(a0 + 96, s1);
    wa10 = wcvt(a1 +  0, s1); wa11 = wcvt(a1 + 32, s1);
    wa12 = wcvt(a1 + 64, s1); wa13 = wcvt(a1 + 96, s1);
    wa20 = wcvt(a2 +  0, s2); wa21 = wcvt(a2 + 32, s2);
    wa22 = wcvt(a2 + 64, s2); wa23 = wcvt(a2 + 96, s2);
    wa30 = wcvt(a3 +  0, s1); wa31 = wcvt(a3 + 32, s1);
    wa32 = wcvt(a3 + 64, s1); wa33 = wcvt(a3 + 96, s1);
    const float* b0p = a0 + (size_t)64 * H_SZ;
    const float* b1p = a1 + (size_t)64 * H_SZ;
    const float* b2p = a2 + (size_t)64 * H_SZ;
    const float* b3p = a3 + (size_t)64 * H_SZ;
    wb00 = wcvt(b0p +  0, s1); wb01 = wcvt(b0p + 32, s1);
    wb02 = wcvt(b0p + 64, s1); wb03 = wcvt(b0p + 96, s1);
    wb10 = wcvt(b1p +  0, s1); wb11 = wcvt(b1p + 32, s1);
    wb12 = wcvt(b1p + 64, s1); wb13 = wcvt(b1p + 96, s1);
    wb20 = wcvt(b2p +  0, s2); wb21 = wcvt(b2p + 32, s2);
    wb22 = wcvt(b2p + 64, s2); wb23 = wcvt(b2p + 96, s2);
    wb30 = wcvt(b3p +  0, s1); wb31 = wcvt(b3p + 32, s1);
    wb32 = wcvt(b3p + 64, s1); wb33 = wcvt(b3p + 96, s1);
  }

  float wtA = -LOG2E * w_tp[col];
  float btA = -LOG2E * b_tp[col];
  float wtB = -LOG2E * w_tp[col + 64];
  float btB = -LOG2E * b_tp[col + 64];
  const float am  = (tt == 2) ? 2.0f : 1.0f;
  const float aa  = (tt == 2) ? -1.0f : 0.0f;
  const bool  odd = (tt & 1) != 0;

  ((_Float16*)hbuf)[tid] = (_Float16)0.0f;   // 2*128 = 256 = blockDim
  __syncthreads();

  // Per-thread gate-x rows (transposed layout): 2048 consecutive f16 each.
  const _Float16* gxr0 = gx + ((size_t)b * G4 + j0) * S_LEN;
  const _Float16* gxr1 = gx + ((size_t)b * G4 + j1) * S_LEN;
  const size_t bH = (size_t)b * H_SZ;

  // Double-buffered half8 blocks, 2 blocks (~16 substeps) ahead of use.
  half8 cur0 = *(const half8*)(gxr0 + 255 * 8);
  half8 cur1 = *(const half8*)(gxr1 + 255 * 8);
  half8 nxt0 = *(const half8*)(gxr0 + 254 * 8);
  half8 nxt1 = *(const half8*)(gxr1 + 254 * 8);

  float cA = 0.0f, cB = 0.0f;

  for (int blk = 255; blk >= 0; --blk) {
    PIN_A();
    PIN_B();
    const int pfb = (blk >= 2) ? blk - 2 : 0;
    half8 fut0 = *(const half8*)(gxr0 + pfb * 8);
    half8 fut1 = *(const half8*)(gxr1 + pfb * 8);
    const floatx4 tmA = *(const floatx4*)(&tml[blk * 8 + 4]); // t = +4..+7
    const floatx4 tmB = *(const floatx4*)(&tml[blk * 8 + 0]); // t = +0..+3

    // 8 substeps: t = blk*8+7 down to blk*8 (ping-pong parity returns to 0)
    SUB2(7, tmA.w, 0, 1)
    SUB2(6, tmA.z, 1, 0)
    SUB2(5, tmA.y, 0, 1)
    SUB2(4, tmA.x, 1, 0)
    SUB2(3, tmB.w, 0, 1)
    SUB2(2, tmB.z, 1, 0)
    SUB2(1, tmB.y, 0, 1)
    SUB2(0, tmB.x, 1, 0)

    cur0 = nxt0; nxt0 = fut0;
    cur1 = nxt1; nxt1 = fut1;
  }
}

// ---------------------------------------------------------------------------
extern "C" void kernel_launch(void* const* d_in, const int* in_sizes, int n_in,
                              void* d_out, int out_size, void* d_ws, size_t ws_size,
                              hipStream_t stream) {
  const float* input = (const float*)d_in[0];   // (S,B,D)
  const float* timep = (const float*)d_in[1];   // (S,B,1)
  const float* W_ih  = (const float*)d_in[2];   // (4H,D)
  const float* W_hh  = (const float*)d_in[3];   // (4H,H)
  const float* bias  = (const float*)d_in[4];   // (4H,)
  const float* w_t   = (const float*)d_in[5];   // (H,)
  const float* b_t   = (const float*)d_in[6];   // (H,)
  float* out = (float*)d_out;

  _Float16* gx = (_Float16*)d_ws;   // 64*512*2048*2 = 128 MiB, [b][n][t]

  gx_gemm<<<dim3(S_LEN / 256, B_SZ), dim3(256), 0, stream>>>(
      input, W_ih, bias, gx);

  lstm_rev<<<dim3(B_SZ), dim3(256), 0, stream>>>(
      gx, timep, W_hh, w_t, b_t, out);
}